// Round 7
// baseline (71.819 us; speedup 1.0000x reference)
//
#include <hip/hip_runtime.h>
#include <hip/hip_bf16.h>

// CosSim2D: inputs (32,64,64,64) f32, w (1,576,128) f32, p (128), q (1)
// out (32,64,64,128) f32.
// R7 = R3 geometry + R4 B-layout: 1-row blocks (2048, 5/CU -> turnover
// overlaps store drain with round-2 compute), fragment-contiguous B
// (coalesced 1KB wave loads), fused fp32 norm in staging, NORMAL stores
// (NT scalar stores caused 1.57x write amplification in R6).

typedef short bf16x8 __attribute__((ext_vector_type(8)));
typedef float f32x4 __attribute__((ext_vector_type(4)));

__device__ __forceinline__ unsigned short f2bf(float f) {
    union { float f; unsigned int u; } v; v.f = f;
    unsigned int u = v.u;
    unsigned int r = (u + 0x7fffu + ((u >> 16) & 1u)) >> 16;  // RNE
    return (unsigned short)r;
}

// ---- pre-kernel: normalize w columns (fp32), store bf16 fragment-contiguous:
// wn2[((tap*2 + kc)*128 + n)*32 + koff] = w_hat[k = tap*64 + kc*32 + koff][n]
__global__ void prep_w_kernel(const float* __restrict__ w,
                              unsigned short* __restrict__ wn2) {
    const int n = blockIdx.x;
    const int lane = threadIdx.x;
    float vals[9];
    float s = 0.f;
#pragma unroll
    for (int i = 0; i < 9; ++i) {
        float v = w[(i * 64 + lane) * 128 + n];
        vals[i] = v;
        s += v * v;
    }
#pragma unroll
    for (int off = 1; off < 64; off <<= 1) s += __shfl_xor(s, off);
    const float inv = 1.0f / sqrtf(fmaxf(s, 1e-12f));
    const int kc = lane >> 5, koff = lane & 31;
#pragma unroll
    for (int i = 0; i < 9; ++i)
        wn2[((i * 2 + kc) * 128 + n) * 32 + koff] = f2bf(vals[i] * inv);
}

// ---- main: one block = (image b, output row y); 64 pixels x 128 kernels
__global__ __launch_bounds__(256, 5) void cossim_main(
    const float* __restrict__ in, const unsigned short* __restrict__ wn,
    const float* __restrict__ p, const float* __restrict__ q,
    float* __restrict__ out) {
    // A: [3 rows][66 cols (zero-pad 0,65)][72 ch (64 + 16B pad)] bf16 = 28512 B
    __shared__ unsigned short A[3 * 66 * 72];
    __shared__ float rcsum[192];   // per-(row,col) fp32 square-sums
    __shared__ float xni[64];      // per-pixel 1/(||x||+q_eff)
    __shared__ float pfs[128];     // exp(p/P_SCALE)

    const int tid = (int)threadIdx.x;
    // bijective XCD swizzle: 2048 blocks, 8 XCDs, 256 consecutive l per XCD
    const int l = ((int)blockIdx.x & 7) * 256 + ((int)blockIdx.x >> 3);
    const int b = l >> 6, y = l & 63;

    if (tid < 128) pfs[tid] = expf(p[tid] * 0.2f);

    // ---- stage 3 input rows (y-1..y+1) + fused fp32 norm partials
    if (tid < 192) {
        const int r = tid >> 6;        // staged row 0..2
        const int col = tid & 63;
        const int row = y + r - 1;
        unsigned short* dst = &A[(r * 66 + col + 1) * 72];
        float s = 0.f;
        if ((unsigned)row < 64u) {
            const float4* src = reinterpret_cast<const float4*>(
                in + (size_t)b * 262144 + row * 4096 + col * 64);
#pragma unroll
            for (int it = 0; it < 8; ++it) {
                float4 v0 = src[2 * it];
                float4 v1 = src[2 * it + 1];
                s += v0.x * v0.x + v0.y * v0.y + v0.z * v0.z + v0.w * v0.w;
                s += v1.x * v1.x + v1.y * v1.y + v1.z * v1.z + v1.w * v1.w;
                union { float f; unsigned u; } ux, uy, uz, uw;
                uint4 pk;
                ux.f = v0.x; uy.f = v0.y; uz.f = v0.z; uw.f = v0.w;
                pk.x = __builtin_amdgcn_perm(uy.u + 0x8000u, ux.u + 0x8000u, 0x07060302u);
                pk.y = __builtin_amdgcn_perm(uw.u + 0x8000u, uz.u + 0x8000u, 0x07060302u);
                ux.f = v1.x; uy.f = v1.y; uz.f = v1.z; uw.f = v1.w;
                pk.z = __builtin_amdgcn_perm(uy.u + 0x8000u, ux.u + 0x8000u, 0x07060302u);
                pk.w = __builtin_amdgcn_perm(uw.u + 0x8000u, uz.u + 0x8000u, 0x07060302u);
                *reinterpret_cast<uint4*>(dst + it * 8) = pk;
            }
        } else {
            uint4 z; z.x = z.y = z.z = z.w = 0u;
#pragma unroll
            for (int it = 0; it < 8; ++it)
                *reinterpret_cast<uint4*>(dst + it * 8) = z;
        }
        rcsum[tid] = s;
    } else {
        const int t = tid - 192;   // 48 used: 3 rows x 2 sides x 8 chunks
        if (t < 48) {
            const int seg = t >> 3, u = t & 7;
            const int r = seg >> 1, side = seg & 1;
            uint4 z; z.x = z.y = z.z = z.w = 0u;
            *reinterpret_cast<uint4*>(&A[(r * 66 + side * 65) * 72 + u * 8]) = z;
        }
    }
    __syncthreads();

    // ---- per-pixel 1/(||x||+q_eff) from fp32 partials
    if (tid < 64) {
        const float qe = expf(q[0] * (-1.0f / 0.3f));
        const int x = tid;
        float s = 0.f;
#pragma unroll
        for (int dy = 0; dy < 3; ++dy) {
            const float* rs = &rcsum[dy * 64];
            if (x > 0) s += rs[x - 1];
            s += rs[x];
            if (x < 63) s += rs[x + 1];
        }
        xni[tid] = 1.0f / (sqrtf(fmaxf(s, 1e-12f)) + qe);
    }

    // ---- MFMA loop: wave grid 2M x 2N; wave owns 32 pixels x 64 n
    const int wv = tid >> 6, lane = tid & 63;
    const int lr = lane & 15, lg = lane >> 4;
    const int wm = wv >> 1, wnh = wv & 1;
    f32x4 acc[2][4] = {};
    // fragment-contiguous B base for this lane: +nf*512 shorts selects nf
    const unsigned short* wB = wn + (wnh * 64 + lr) * 32 + lg * 8;

#pragma unroll
    for (int dy = 0; dy < 3; ++dy) {
#pragma unroll
        for (int dx = 0; dx < 3; ++dx) {
            const int tap = dy * 3 + dx;
#pragma unroll
            for (int kc = 0; kc < 2; ++kc) {
                const unsigned short* wt = wB + (tap * 2 + kc) * 4096;
                bf16x8 b0 = *reinterpret_cast<const bf16x8*>(wt);
                bf16x8 b1 = *reinterpret_cast<const bf16x8*>(wt + 512);
                bf16x8 b2 = *reinterpret_cast<const bf16x8*>(wt + 1024);
                bf16x8 b3 = *reinterpret_cast<const bf16x8*>(wt + 1536);
                const unsigned short* abase =
                    &A[(dy * 66 + wm * 32 + lr + dx) * 72 + kc * 32 + lg * 8];
#pragma unroll
                for (int mf = 0; mf < 2; ++mf) {
                    bf16x8 av = *reinterpret_cast<const bf16x8*>(abase + mf * 16 * 72);
                    acc[mf][0] = __builtin_amdgcn_mfma_f32_16x16x32_bf16(av, b0, acc[mf][0], 0, 0, 0);
                    acc[mf][1] = __builtin_amdgcn_mfma_f32_16x16x32_bf16(av, b1, acc[mf][1], 0, 0, 0);
                    acc[mf][2] = __builtin_amdgcn_mfma_f32_16x16x32_bf16(av, b2, acc[mf][2], 0, 0, 0);
                    acc[mf][3] = __builtin_amdgcn_mfma_f32_16x16x32_bf16(av, b3, acc[mf][3], 0, 0, 0);
                }
            }
        }
    }
    __syncthreads();   // xni/pfs visibility before epilogue

    // ---- epilogue: sim = acc * xni; out = sign * (|sim|+eps)^p_eff
    float* orow = out + ((size_t)(b * 64 + y) * 64) * 128;
#pragma unroll
    for (int mf = 0; mf < 2; ++mf) {
#pragma unroll
        for (int i = 0; i < 4; ++i) {
            const int px = wm * 32 + mf * 16 + lg * 4 + i;  // C/D: row=(lane>>4)*4+reg
            const float xn = xni[px];
#pragma unroll
            for (int nf = 0; nf < 4; ++nf) {
                const int n = wnh * 64 + nf * 16 + lr;
                float sim = acc[mf][nf][i] * xn;
                float aa = fabsf(sim) + 1e-6f;
                float r = exp2f(pfs[n] * log2f(aa));
                orow[(size_t)px * 128 + n] = copysignf(r, sim);
            }
        }
    }
}

extern "C" void kernel_launch(void* const* d_in, const int* in_sizes, int n_in,
                              void* d_out, int out_size, void* d_ws, size_t ws_size,
                              hipStream_t stream) {
    (void)in_sizes; (void)n_in; (void)out_size; (void)ws_size;
    const float* in = (const float*)d_in[0];
    const float* w  = (const float*)d_in[1];
    const float* p  = (const float*)d_in[2];
    const float* q  = (const float*)d_in[3];
    float* out = (float*)d_out;
    unsigned short* wn = (unsigned short*)d_ws;  // 18*128*32 bf16 = 147456 B

    prep_w_kernel<<<128, 64, 0, stream>>>(w, wn);
    cossim_main<<<2048, 256, 0, stream>>>(in, wn, p, q, out);
}

// Round 8
// 70.129 us; speedup vs baseline: 1.0241x; 1.0241x over previous
//
#include <hip/hip_runtime.h>
#include <hip/hip_bf16.h>

// CosSim2D: inputs (32,64,64,64) f32, w (1,576,128) f32, p (128), q (1)
// out (32,64,64,128) f32.
// R8 = R7 turnover geometry (1-row blocks, 2048, 5/CU) + line-complete
// stores: epilogue routed through LDS (A-tile space reused), out written as
// px-major float4 wave-stores = 8 whole 128B lines per instruction. Tests
// the partial-line-RMW write-amplification theory from R3/R6/R7.

typedef short bf16x8 __attribute__((ext_vector_type(8)));
typedef float f32x4 __attribute__((ext_vector_type(4)));

__device__ __forceinline__ unsigned short f2bf(float f) {
    union { float f; unsigned int u; } v; v.f = f;
    unsigned int u = v.u;
    unsigned int r = (u + 0x7fffu + ((u >> 16) & 1u)) >> 16;  // RNE
    return (unsigned short)r;
}

// ---- pre-kernel: normalize w columns (fp32), store bf16 fragment-contiguous:
// wn2[((tap*2 + kc)*128 + n)*32 + koff] = w_hat[k = tap*64 + kc*32 + koff][n]
__global__ void prep_w_kernel(const float* __restrict__ w,
                              unsigned short* __restrict__ wn2) {
    const int n = blockIdx.x;
    const int lane = threadIdx.x;
    float vals[9];
    float s = 0.f;
#pragma unroll
    for (int i = 0; i < 9; ++i) {
        float v = w[(i * 64 + lane) * 128 + n];
        vals[i] = v;
        s += v * v;
    }
#pragma unroll
    for (int off = 1; off < 64; off <<= 1) s += __shfl_xor(s, off);
    const float inv = 1.0f / sqrtf(fmaxf(s, 1e-12f));
    const int kc = lane >> 5, koff = lane & 31;
#pragma unroll
    for (int i = 0; i < 9; ++i)
        wn2[((i * 2 + kc) * 128 + n) * 32 + koff] = f2bf(vals[i] * inv);
}

#define OBLD 68   // out-staging row stride in floats (16B-aligned, bank-skewed)

// ---- main: one block = (image b, output row y); 64 pixels x 128 kernels
__global__ __launch_bounds__(256, 5) void cossim_main(
    const float* __restrict__ in, const unsigned short* __restrict__ wn,
    const float* __restrict__ p, const float* __restrict__ q,
    float* __restrict__ out) {
    // A: [3 rows][66 cols (zero-pad 0,65)][72 ch] bf16 = 28512 B.
    // After MFMA, the same space is reused as OB[64 px][68] f32 (17408 B)
    // for the store-transpose.
    __shared__ __align__(16) unsigned char smemRaw[3 * 66 * 72 * 2];
    unsigned short* A = reinterpret_cast<unsigned short*>(smemRaw);
    float* OB = reinterpret_cast<float*>(smemRaw);
    __shared__ float rcsum[192];   // per-(row,col) fp32 square-sums
    __shared__ float xni[64];      // per-pixel 1/(||x||+q_eff)
    __shared__ float pfs[128];     // exp(p/P_SCALE)

    const int tid = (int)threadIdx.x;
    // bijective XCD swizzle: 2048 blocks, 8 XCDs, 256 consecutive l per XCD
    const int l = ((int)blockIdx.x & 7) * 256 + ((int)blockIdx.x >> 3);
    const int b = l >> 6, y = l & 63;

    if (tid < 128) pfs[tid] = expf(p[tid] * 0.2f);

    // ---- stage 3 input rows (y-1..y+1) + fused fp32 norm partials
    if (tid < 192) {
        const int r = tid >> 6;        // staged row 0..2
        const int col = tid & 63;
        const int row = y + r - 1;
        unsigned short* dst = &A[(r * 66 + col + 1) * 72];
        float s = 0.f;
        if ((unsigned)row < 64u) {
            const float4* src = reinterpret_cast<const float4*>(
                in + (size_t)b * 262144 + row * 4096 + col * 64);
#pragma unroll
            for (int it = 0; it < 8; ++it) {
                float4 v0 = src[2 * it];
                float4 v1 = src[2 * it + 1];
                s += v0.x * v0.x + v0.y * v0.y + v0.z * v0.z + v0.w * v0.w;
                s += v1.x * v1.x + v1.y * v1.y + v1.z * v1.z + v1.w * v1.w;
                union { float f; unsigned u; } ux, uy, uz, uw;
                uint4 pk;
                ux.f = v0.x; uy.f = v0.y; uz.f = v0.z; uw.f = v0.w;
                pk.x = __builtin_amdgcn_perm(uy.u + 0x8000u, ux.u + 0x8000u, 0x07060302u);
                pk.y = __builtin_amdgcn_perm(uw.u + 0x8000u, uz.u + 0x8000u, 0x07060302u);
                ux.f = v1.x; uy.f = v1.y; uz.f = v1.z; uw.f = v1.w;
                pk.z = __builtin_amdgcn_perm(uy.u + 0x8000u, ux.u + 0x8000u, 0x07060302u);
                pk.w = __builtin_amdgcn_perm(uw.u + 0x8000u, uz.u + 0x8000u, 0x07060302u);
                *reinterpret_cast<uint4*>(dst + it * 8) = pk;
            }
        } else {
            uint4 z; z.x = z.y = z.z = z.w = 0u;
#pragma unroll
            for (int it = 0; it < 8; ++it)
                *reinterpret_cast<uint4*>(dst + it * 8) = z;
        }
        rcsum[tid] = s;
    } else {
        const int t = tid - 192;   // 48 used: 3 rows x 2 sides x 8 chunks
        if (t < 48) {
            const int seg = t >> 3, u = t & 7;
            const int r = seg >> 1, side = seg & 1;
            uint4 z; z.x = z.y = z.z = z.w = 0u;
            *reinterpret_cast<uint4*>(&A[(r * 66 + side * 65) * 72 + u * 8]) = z;
        }
    }
    __syncthreads();

    // ---- per-pixel 1/(||x||+q_eff) from fp32 partials
    if (tid < 64) {
        const float qe = expf(q[0] * (-1.0f / 0.3f));
        const int x = tid;
        float s = 0.f;
#pragma unroll
        for (int dy = 0; dy < 3; ++dy) {
            const float* rs = &rcsum[dy * 64];
            if (x > 0) s += rs[x - 1];
            s += rs[x];
            if (x < 63) s += rs[x + 1];
        }
        xni[tid] = 1.0f / (sqrtf(fmaxf(s, 1e-12f)) + qe);
    }

    // ---- MFMA loop: wave grid 2M x 2N; wave owns 32 pixels x 64 n
    const int wv = tid >> 6, lane = tid & 63;
    const int lr = lane & 15, lg = lane >> 4;
    const int wm = wv >> 1, wnh = wv & 1;
    f32x4 acc[2][4] = {};
    const unsigned short* wB = wn + (wnh * 64 + lr) * 32 + lg * 8;

#pragma unroll
    for (int dy = 0; dy < 3; ++dy) {
#pragma unroll
        for (int dx = 0; dx < 3; ++dx) {
            const int tap = dy * 3 + dx;
#pragma unroll
            for (int kc = 0; kc < 2; ++kc) {
                const unsigned short* wt = wB + (tap * 2 + kc) * 4096;
                bf16x8 b0 = *reinterpret_cast<const bf16x8*>(wt);
                bf16x8 b1 = *reinterpret_cast<const bf16x8*>(wt + 512);
                bf16x8 b2 = *reinterpret_cast<const bf16x8*>(wt + 1024);
                bf16x8 b3 = *reinterpret_cast<const bf16x8*>(wt + 1536);
                const unsigned short* abase =
                    &A[(dy * 66 + wm * 32 + lr + dx) * 72 + kc * 32 + lg * 8];
#pragma unroll
                for (int mf = 0; mf < 2; ++mf) {
                    bf16x8 av = *reinterpret_cast<const bf16x8*>(abase + mf * 16 * 72);
                    acc[mf][0] = __builtin_amdgcn_mfma_f32_16x16x32_bf16(av, b0, acc[mf][0], 0, 0, 0);
                    acc[mf][1] = __builtin_amdgcn_mfma_f32_16x16x32_bf16(av, b1, acc[mf][1], 0, 0, 0);
                    acc[mf][2] = __builtin_amdgcn_mfma_f32_16x16x32_bf16(av, b2, acc[mf][2], 0, 0, 0);
                    acc[mf][3] = __builtin_amdgcn_mfma_f32_16x16x32_bf16(av, b3, acc[mf][3], 0, 0, 0);
                }
            }
        }
    }
    __syncthreads();   // MFMA A-reads done (A space now reusable) + xni visible

    // ---- epilogue via LDS transpose, two n-half passes; line-complete stores
    float* orow = out + (size_t)(b * 64 + y) * 8192;
#pragma unroll
    for (int h = 0; h < 2; ++h) {
        if (wnh == h) {
#pragma unroll
            for (int mf = 0; mf < 2; ++mf) {
#pragma unroll
                for (int i = 0; i < 4; ++i) {
                    const int px = wm * 32 + mf * 16 + lg * 4 + i;
                    const float xn = xni[px];
#pragma unroll
                    for (int nf = 0; nf < 4; ++nf) {
                        const int n = nf * 16 + lr;
                        float sim = acc[mf][nf][i] * xn;
                        float aa = fabsf(sim) + 1e-6f;
                        float r = exp2f(pfs[h * 64 + n] * log2f(aa));
                        OB[px * OBLD + n] = copysignf(r, sim);
                    }
                }
            }
        }
        __syncthreads();   // OB half ready
#pragma unroll
        for (int j = 0; j < 4; ++j) {
            const int f = tid + 256 * j;      // 0..1023
            const int px = f >> 4, qq = f & 15;
            float4 v = *reinterpret_cast<const float4*>(&OB[px * OBLD + qq * 4]);
            *reinterpret_cast<float4*>(orow + px * 128 + h * 64 + qq * 4) = v;
        }
        if (h == 0) __syncthreads();   // reads done before pass-1 overwrites
    }
}

extern "C" void kernel_launch(void* const* d_in, const int* in_sizes, int n_in,
                              void* d_out, int out_size, void* d_ws, size_t ws_size,
                              hipStream_t stream) {
    (void)in_sizes; (void)n_in; (void)out_size; (void)ws_size;
    const float* in = (const float*)d_in[0];
    const float* w  = (const float*)d_in[1];
    const float* p  = (const float*)d_in[2];
    const float* q  = (const float*)d_in[3];
    float* out = (float*)d_out;
    unsigned short* wn = (unsigned short*)d_ws;  // 18*128*32 bf16 = 147456 B

    prep_w_kernel<<<128, 64, 0, stream>>>(w, wn);
    cossim_main<<<2048, 256, 0, stream>>>(in, wn, p, q, out);
}

// Round 9
// 43.355 us; speedup vs baseline: 1.6565x; 1.6176x over previous
//
#include <hip/hip_runtime.h>
#include <hip/hip_bf16.h>

// CosSim2D: inputs (32,64,64,64) f32, w (1,576,128) f32, p (128), q (1)
// out (32,64,64,128) f32.
// R9 = R4 (2-row blocks, 1024 grid, fragment-contiguous B, fused fp32 norm)
//  + explicit 1-step B-fragment software pipeline (hide L2 latency under MFMA)
//  + barrier-free epilogue (sync moved before MFMA; stores stagger per-wave).

typedef short bf16x8 __attribute__((ext_vector_type(8)));
typedef float f32x4 __attribute__((ext_vector_type(4)));

__device__ __forceinline__ unsigned short f2bf(float f) {
    union { float f; unsigned int u; } v; v.f = f;
    unsigned int u = v.u;
    unsigned int r = (u + 0x7fffu + ((u >> 16) & 1u)) >> 16;  // RNE
    return (unsigned short)r;
}

// ---- pre-kernel: normalize w columns (fp32), store bf16 fragment-contiguous:
// wn2[((tap*2 + kc)*128 + n)*32 + koff] = w_hat[k = tap*64 + kc*32 + koff][n]
__global__ void prep_w_kernel(const float* __restrict__ w,
                              unsigned short* __restrict__ wn2) {
    const int n = blockIdx.x;
    const int lane = threadIdx.x;
    float vals[9];
    float s = 0.f;
#pragma unroll
    for (int i = 0; i < 9; ++i) {
        float v = w[(i * 64 + lane) * 128 + n];
        vals[i] = v;
        s += v * v;
    }
#pragma unroll
    for (int off = 1; off < 64; off <<= 1) s += __shfl_xor(s, off);
    const float inv = 1.0f / sqrtf(fmaxf(s, 1e-12f));
    const int kc = lane >> 5, koff = lane & 31;
#pragma unroll
    for (int i = 0; i < 9; ++i)
        wn2[((i * 2 + kc) * 128 + n) * 32 + koff] = f2bf(vals[i] * inv);
}

// ---- main: one block = (image b, output rows y0,y0+1); 128 pixels x 128 n
__global__ __launch_bounds__(256, 4) void cossim_main(
    const float* __restrict__ in, const unsigned short* __restrict__ wn,
    const float* __restrict__ p, const float* __restrict__ q,
    float* __restrict__ out) {
    // A: [4 rows][66 cols (zero-pad 0,65)][72 ch (64 + 16B pad)] bf16 = 38016 B
    __shared__ unsigned short A[4 * 66 * 72];
    __shared__ float rcsum[256];   // per-(row,col) fp32 square-sums
    __shared__ float xni[128];     // per-pixel 1/(||x||+q_eff)
    __shared__ float pfs[128];     // exp(p/P_SCALE)

    const int tid = (int)threadIdx.x;
    // bijective XCD swizzle: 1024 blocks, 8 XCDs, 128 consecutive l per XCD
    const int l = ((int)blockIdx.x & 7) * 128 + ((int)blockIdx.x >> 3);
    const int b = l >> 5, y0 = (l & 31) * 2;

    if (tid < 128) pfs[tid] = expf(p[tid] * 0.2f);

    // ---- stage 4 input rows (y0-1 .. y0+2) + fused fp32 norm partials
    {
        const int r = tid >> 6;        // staged row 0..3
        const int col = tid & 63;
        const int row = y0 + r - 1;
        unsigned short* dst = &A[(r * 66 + col + 1) * 72];
        float s = 0.f;
        if ((unsigned)row < 64u) {
            const float4* src = reinterpret_cast<const float4*>(
                in + (size_t)b * 262144 + row * 4096 + col * 64);
#pragma unroll
            for (int it = 0; it < 8; ++it) {
                float4 v0 = src[2 * it];
                float4 v1 = src[2 * it + 1];
                s += v0.x * v0.x + v0.y * v0.y + v0.z * v0.z + v0.w * v0.w;
                s += v1.x * v1.x + v1.y * v1.y + v1.z * v1.z + v1.w * v1.w;
                union { float f; unsigned u; } ux, uy, uz, uw;
                uint4 pk;
                ux.f = v0.x; uy.f = v0.y; uz.f = v0.z; uw.f = v0.w;
                pk.x = __builtin_amdgcn_perm(uy.u + 0x8000u, ux.u + 0x8000u, 0x07060302u);
                pk.y = __builtin_amdgcn_perm(uw.u + 0x8000u, uz.u + 0x8000u, 0x07060302u);
                ux.f = v1.x; uy.f = v1.y; uz.f = v1.z; uw.f = v1.w;
                pk.z = __builtin_amdgcn_perm(uy.u + 0x8000u, ux.u + 0x8000u, 0x07060302u);
                pk.w = __builtin_amdgcn_perm(uw.u + 0x8000u, uz.u + 0x8000u, 0x07060302u);
                *reinterpret_cast<uint4*>(dst + it * 8) = pk;
            }
        } else {
            uint4 z; z.x = z.y = z.z = z.w = 0u;
#pragma unroll
            for (int it = 0; it < 8; ++it)
                *reinterpret_cast<uint4*>(dst + it * 8) = z;
        }
        rcsum[tid] = s;
    }
    if (tid < 64) {  // zero border cols 0 and 65, all 4 rows
        const int r = tid >> 4, side = (tid >> 3) & 1, ch = (tid & 7) * 8;
        uint4 z; z.x = z.y = z.z = z.w = 0u;
        *reinterpret_cast<uint4*>(&A[(r * 66 + side * 65) * 72 + ch]) = z;
    }
    __syncthreads();

    // ---- per-pixel 1/(||x||+q_eff) from fp32 partials
    if (tid < 128) {
        const int ry = tid >> 6, x = tid & 63;
        const float qe = expf(q[0] * (-1.0f / 0.3f));
        float s = 0.f;
#pragma unroll
        for (int dy = 0; dy < 3; ++dy) {
            const float* rs = &rcsum[(ry + dy) * 64];
            if (x > 0) s += rs[x - 1];
            s += rs[x];
            if (x < 63) s += rs[x + 1];
        }
        xni[tid] = 1.0f / (sqrtf(fmaxf(s, 1e-12f)) + qe);
    }
    __syncthreads();   // xni/pfs ready -> epilogue below needs NO barrier

    // ---- MFMA loop: wave grid 2M x 2N; wave owns 64 pixels x 64 n.
    // B fragments explicitly pipelined one kc-step ahead (bc* = current,
    // bn* = next) so the 4 L2 loads of step s+1 fly under step s's 16 MFMAs.
    const int wv = tid >> 6, lane = tid & 63;
    const int lr = lane & 15, lg = lane >> 4;
    const int wm = wv >> 1, wnh = wv & 1;
    f32x4 acc[4][4] = {};
    const unsigned short* wB = wn + (wnh * 64 + lr) * 32 + lg * 8;

    bf16x8 bc0 = *reinterpret_cast<const bf16x8*>(wB);
    bf16x8 bc1 = *reinterpret_cast<const bf16x8*>(wB + 512);
    bf16x8 bc2 = *reinterpret_cast<const bf16x8*>(wB + 1024);
    bf16x8 bc3 = *reinterpret_cast<const bf16x8*>(wB + 1536);

#pragma unroll
    for (int s = 0; s < 18; ++s) {
        bf16x8 bn0, bn1, bn2, bn3;
        if (s + 1 < 18) {
            const unsigned short* wt = wB + (s + 1) * 4096;
            bn0 = *reinterpret_cast<const bf16x8*>(wt);
            bn1 = *reinterpret_cast<const bf16x8*>(wt + 512);
            bn2 = *reinterpret_cast<const bf16x8*>(wt + 1024);
            bn3 = *reinterpret_cast<const bf16x8*>(wt + 1536);
        }
        const int dy = s / 6, dx = (s >> 1) % 3, kc = s & 1;
        const unsigned short* abase =
            &A[((wm + dy) * 66 + lr + dx) * 72 + kc * 32 + lg * 8];
#pragma unroll
        for (int mf = 0; mf < 4; ++mf) {
            bf16x8 av = *reinterpret_cast<const bf16x8*>(abase + mf * 16 * 72);
            acc[mf][0] = __builtin_amdgcn_mfma_f32_16x16x32_bf16(av, bc0, acc[mf][0], 0, 0, 0);
            acc[mf][1] = __builtin_amdgcn_mfma_f32_16x16x32_bf16(av, bc1, acc[mf][1], 0, 0, 0);
            acc[mf][2] = __builtin_amdgcn_mfma_f32_16x16x32_bf16(av, bc2, acc[mf][2], 0, 0, 0);
            acc[mf][3] = __builtin_amdgcn_mfma_f32_16x16x32_bf16(av, bc3, acc[mf][3], 0, 0, 0);
        }
        bc0 = bn0; bc1 = bn1; bc2 = bn2; bc3 = bn3;
    }

    // ---- epilogue (barrier-free): sim = acc*xni; out = sign*(|sim|+eps)^p
    float* orow = out + ((size_t)(b * 64 + y0 + wm) * 64) * 128;
#pragma unroll
    for (int mf = 0; mf < 4; ++mf) {
#pragma unroll
        for (int i = 0; i < 4; ++i) {
            const int pix = mf * 16 + lg * 4 + i;   // C/D: row=(lane>>4)*4+reg
            const float xn = xni[wm * 64 + pix];
#pragma unroll
            for (int nf = 0; nf < 4; ++nf) {
                const int n = wnh * 64 + nf * 16 + lr;
                float sim = acc[mf][nf][i] * xn;
                float aa = fabsf(sim) + 1e-6f;
                float r = exp2f(pfs[n] * log2f(aa));
                orow[(size_t)pix * 128 + n] = copysignf(r, sim);
            }
        }
    }
}

extern "C" void kernel_launch(void* const* d_in, const int* in_sizes, int n_in,
                              void* d_out, int out_size, void* d_ws, size_t ws_size,
                              hipStream_t stream) {
    (void)in_sizes; (void)n_in; (void)out_size; (void)ws_size;
    const float* in = (const float*)d_in[0];
    const float* w  = (const float*)d_in[1];
    const float* p  = (const float*)d_in[2];
    const float* q  = (const float*)d_in[3];
    float* out = (float*)d_out;
    unsigned short* wn = (unsigned short*)d_ws;  // 18*128*32 bf16 = 147456 B

    prep_w_kernel<<<128, 64, 0, stream>>>(w, wn);
    cossim_main<<<1024, 256, 0, stream>>>(in, wn, p, q, out);
}